// Round 9
// baseline (301.037 us; speedup 1.0000x reference)
//
#include <hip/hip_runtime.h>
#include <stdint.h>

// Single-dispatch producer/consumer binary-morphology skeleton.
// Waves 0..1023 bit-pack the input in frontier order (flag per 4-row unit,
// device-scope release). Waves 1024..2047 poll flags for images 0-7 and run
// register morphology immediately -> their 67MB write overlaps the 67MB pack
// read. Packer waves then take images 8-15. Morphology math identical to R8
// (verified exact): lane holds RPL rows x 3 u64 words, vertical via __shfl.

typedef unsigned long long u64;
typedef float vfloat4 __attribute__((ext_vector_type(4)));

#define WIDTH   1024
#define HEIGHT  1024
#define NIMG    16
#define WPR     16          // u64 words per image row
#define RPL     3           // rows per lane (wave covers 192 rows)
#define HALO    17
#define BVALID  128         // valid output rows per band; 8 bands cover 1024
#define NBANDS  8
#define NBLK    512
#define NTHR    256
#define PACKW   1024        // packer waves
#define NUNITS  4096        // 16384 rows / 4 rows per flag unit

// ---------------- wave-edge shuffles (zero beyond wave) ----------------------
__device__ __forceinline__ u64 sh_up(u64 x, int lane) {
    u64 t = __shfl(x, lane - 1);
    return lane == 0 ? 0ULL : t;
}
__device__ __forceinline__ u64 sh_dn(u64 x, int lane) {
    u64 t = __shfl(x, lane + 1);
    return lane == 63 ? 0ULL : t;
}

// One skeleton step, fully in registers (LSB = leftmost pixel). R8-proven.
template <int RM, int CM, bool DIL>
__device__ __forceinline__ void mstep(u64 (&B)[RPL][3], u64 (&O)[RPL][3], int lane) {
    u64 T[RPL][3], M[RPL][3];
    #pragma unroll
    for (int s = 0; s < RPL; ++s) {
        #pragma unroll
        for (int j = 0; j < 3; ++j) {
            u64 c = B[s][j], res = ~0ULL;
            if (CM & 2) res &= c;
            if (CM & 1) res &= (c << 1) | ((j > 0 ? B[s][j - 1] : 0ULL) >> 63);
            if (CM & 4) res &= (c >> 1) | ((j < 2 ? B[s][j + 1] : 0ULL) << 63);
            T[s][j] = res;
        }
    }
    #pragma unroll
    for (int j = 0; j < 3; ++j) {
        u64 up = sh_up(T[RPL - 1][j], lane);
        u64 dn = sh_dn(T[0][j], lane);
        #pragma unroll
        for (int s = 0; s < RPL; ++s) {
            u64 res = ~0ULL;
            if (RM & 2) res &= T[s][j];
            if (RM & 1) res &= (s > 0 ? T[s - 1][j] : up);
            if (RM & 4) res &= (s < RPL - 1 ? T[s + 1][j] : dn);
            M[s][j] = res;
            O[s][j] |= res;
        }
    }
    if (DIL) {
        #pragma unroll
        for (int s = 0; s < RPL; ++s) {
            #pragma unroll
            for (int j = 0; j < 3; ++j) {
                u64 c = M[s][j], res = 0;
                if (CM & 2) res |= c;
                if (CM & 1) res |= (c >> 1) | ((j < 2 ? M[s][j + 1] : 0ULL) << 63);
                if (CM & 4) res |= (c << 1) | ((j > 0 ? M[s][j - 1] : 0ULL) >> 63);
                T[s][j] = res;
            }
        }
        #pragma unroll
        for (int j = 0; j < 3; ++j) {
            u64 up = sh_up(T[RPL - 1][j], lane);
            u64 dn = sh_dn(T[0][j], lane);
            #pragma unroll
            for (int s = 0; s < RPL; ++s) {
                u64 res = 0;
                if (RM & 2) res |= T[s][j];
                if (RM & 1) res |= (s < RPL - 1 ? T[s + 1][j] : dn);
                if (RM & 4) res |= (s > 0 ? T[s - 1][j] : up);
                B[s][j] &= ~res;
            }
        }
    }
}

__global__ __launch_bounds__(NTHR, 2) void skel_kernel(const float* __restrict__ x,
                                                       float* __restrict__ out,
                                                       u64* __restrict__ packed,
                                                       unsigned* __restrict__ flags) {
    __shared__ u64 stage[4][BVALID];
    int lane = threadIdx.x & 63;
    int wv   = threadIdx.x >> 6;
    int W    = blockIdx.x * 4 + wv;               // global wave id, 0..2047

    // ---- pack phase: waves 0..1023, frontier order (round-major units) ------
    if (W < PACKW) {
        for (int k = 0; k < 4; ++k) {
            int u = k * PACKW + W;                // unit = 4 consecutive rows
            u64* ub = packed + (size_t)u * 4 * WPR;
            const float* xb = x + (size_t)u * 4 * WIDTH;
            #pragma unroll
            for (int rr = 0; rr < 4; ++rr) {
                const float* rbase = xb + (size_t)rr * WIDTH;
                u64* pbase = ub + rr * WPR;
                #pragma unroll
                for (int rnd = 0; rnd < 4; ++rnd) {
                    vfloat4 v = *(const vfloat4*)(rbase + rnd * 256 + lane * 4);
                    unsigned nib = (v.x > 0.5f ? 1u : 0u) | (v.y > 0.5f ? 2u : 0u)
                                 | (v.z > 0.5f ? 4u : 0u) | (v.w > 0.5f ? 8u : 0u);
                    u64 n = (u64)nib << (4 * (lane & 15));
                    n |= __shfl_xor(n, 1);
                    n |= __shfl_xor(n, 2);
                    n |= __shfl_xor(n, 4);
                    n |= __shfl_xor(n, 8);
                    if ((lane & 15) == 0) pbase[rnd * 4 + (lane >> 4)] = n;
                }
            }
            __threadfence();                      // release: stores visible device-wide
            if (lane == 0) atomicExch(&flags[u], 1u);
        }
    }

    // ---- morph task: consumers (W>=1024) take imgs 0-7, packers take 8-15 ---
    int T = (W < PACKW) ? (PACKW + W) : (W - PACKW);
    int img  = T >> 7;
    int rem  = T & 127;
    int wcol = rem >> 3;
    int band = rem & 7;
    int bstart = band * BVALID - HALO;            // relative row of lane0,s0

    // wait for the needed 4-row pack units (<=48 flags, one per lane)
    {
        int r0 = bstart > 0 ? bstart : 0;
        int r1 = bstart + 64 * RPL - 1;
        if (r1 > HEIGHT - 1) r1 = HEIGHT - 1;
        int u0 = (img * HEIGHT + r0) >> 2;
        int u1 = (img * HEIGHT + r1) >> 2;
        bool done = (u0 + lane > u1);
        while (true) {
            if (!done)
                done = (__hip_atomic_load(&flags[u0 + lane], __ATOMIC_RELAXED,
                                          __HIP_MEMORY_SCOPE_AGENT) == 1u);
            if (__all(done)) break;
            __builtin_amdgcn_s_sleep(2);
        }
        __threadfence();                          // acquire: invalidate stale L2
    }

    // load 3 rows x 3 words per lane, zero outside image
    const u64* pimg = packed + (size_t)img * HEIGHT * WPR;
    u64 B[RPL][3], O[RPL][3];
    #pragma unroll
    for (int s = 0; s < RPL; ++s) {
        int g = bstart + lane * RPL + s;
        bool rok = (g >= 0 && g < HEIGHT);
        #pragma unroll
        for (int j = 0; j < 3; ++j) {
            int wi = wcol - 1 + j;
            B[s][j] = (rok && wi >= 0 && wi < WPR) ? pimg[(size_t)g * WPR + wi] : 0ULL;
            O[s][j] = 0ULL;
        }
    }

    // 8 structuring elements as (rowmask, colmask) rectangles
    mstep<7, 7, true >(B, O, lane);   // all ones
    mstep<7, 6, true >(B, O, lane);   // cols {1,2}
    mstep<3, 7, true >(B, O, lane);   // rows {0,1}
    mstep<6, 6, true >(B, O, lane);   // rows {1,2} x cols {1,2}
    mstep<7, 2, true >(B, O, lane);   // col {1}
    mstep<2, 7, true >(B, O, lane);   // row {1}
    mstep<3, 2, true >(B, O, lane);   // col {1}, rows {0,1}
    mstep<2, 3, false>(B, O, lane);   // row {1}, cols {0,1}; B unused after

    // isolated-point: 3x3 popcount of O == 1, center word (carry-save)
    u64 Wn[RPL], Cn[RPL], En[RPL], res[RPL];
    #pragma unroll
    for (int s = 0; s < RPL; ++s) {
        Cn[s] = O[s][1];
        Wn[s] = (O[s][1] << 1) | (O[s][0] >> 63);
        En[s] = (O[s][1] >> 1) | (O[s][2] << 63);
    }
    u64 upW = sh_up(Wn[RPL - 1], lane), upC = sh_up(Cn[RPL - 1], lane),
        upE = sh_up(En[RPL - 1], lane);
    u64 dnW = sh_dn(Wn[0], lane), dnC = sh_dn(Cn[0], lane), dnE = sh_dn(En[0], lane);
    #pragma unroll
    for (int s = 0; s < RPL; ++s) {
        u64 ones = 0, twos = 0;
        auto acc = [&](u64 v) { twos |= ones & v; ones ^= v; };
        acc(s > 0 ? Wn[s - 1] : upW);
        acc(s > 0 ? Cn[s - 1] : upC);
        acc(s > 0 ? En[s - 1] : upE);
        acc(Wn[s]); acc(Cn[s]); acc(En[s]);
        acc(s < RPL - 1 ? Wn[s + 1] : dnW);
        acc(s < RPL - 1 ? Cn[s + 1] : dnC);
        acc(s < RPL - 1 ? En[s + 1] : dnE);
        res[s] = ones & ~twos;
    }

    // stage valid rows into this wave's private LDS slice (wave-local RAW:
    // hardware lgkmcnt ordering within the wave, no block barrier needed)
    #pragma unroll
    for (int s = 0; s < RPL; ++s) {
        int v = lane * RPL + s;
        if (v >= HALO && v < HALO + BVALID) stage[wv][v - HALO] = res[s];
    }

    // expand to f32: 4 rows x 16 lanes x float4 per iteration, coalesced
    int gbase = band * BVALID;
    float* obase = out + (size_t)img * HEIGHT * WIDTH + wcol * 64 + (lane & 15) * 4;
    for (int it = 0; it < BVALID / 4; ++it) {
        int t = it * 4 + (lane >> 4);
        u64 word = stage[wv][t];
        unsigned nib = (unsigned)(word >> ((lane & 15) * 4)) & 15u;
        vfloat4 v4;
        v4.x = (nib & 1) ? 1.f : 0.f;
        v4.y = (nib & 2) ? 1.f : 0.f;
        v4.z = (nib & 4) ? 1.f : 0.f;
        v4.w = (nib & 8) ? 1.f : 0.f;
        __builtin_nontemporal_store(v4, (vfloat4*)(obase + (size_t)(gbase + t) * WIDTH));
    }
}

extern "C" void kernel_launch(void* const* d_in, const int* in_sizes, int n_in,
                              void* d_out, int out_size, void* d_ws, size_t ws_size,
                              hipStream_t stream) {
    const float* x = (const float*)d_in[0];
    float* out = (float*)d_out;
    u64* packed = (u64*)d_ws;                                   // 2 MiB
    unsigned* flags = (unsigned*)((char*)d_ws + (size_t)NIMG * HEIGHT * WPR * 8);
    // flags poisoned to 0xAAAAAAAA each launch; producer sets ==1, so no init needed.
    hipLaunchKernelGGL(skel_kernel, dim3(NBLK), dim3(NTHR), 0, stream,
                       x, out, packed, flags);
}

// Round 10
// 115.007 us; speedup vs baseline: 2.6175x; 2.6175x over previous
//
#include <hip/hip_runtime.h>
#include <stdint.h>

// Two-kernel binary-morphology skeleton (R8 structure, pack-MLP tweak).
// Pack: float4 loads (all 4 issued up-front) + nibble + shfl_xor OR-reduce.
// Morph: wave-autonomous REGISTER morphology — lane i holds rows 2i,2i+1 x
// 3 u64 words (center output word + halo word each side; horizontal reach
// is only +/-17px). Vertical neighbors via __shfl lane+/-1. Zero barriers in
// the 8-step chain; one barrier before the LDS-staged coalesced expand.

typedef unsigned long long u64;
typedef float vfloat4 __attribute__((ext_vector_type(4)));

#define WIDTH   1024
#define HEIGHT  1024
#define NIMG    16
#define WPR     16          // u64 words per image row
#define RPL     2           // rows per lane
#define VROWS   128         // rows covered per wave = 64*RPL
#define HALO    17          // 8 steps x (erode+dilate) + iso conv
#define BVALID  94          // VROWS - 2*HALO
#define NBANDS  11          // ceil(1024/94)
#define PACK_ROWS 4

// ---------------- phase 1: binarize + bit-pack, float4 + shfl assembly -------
__global__ __launch_bounds__(256) void pack_kernel(const float* __restrict__ x,
                                                   u64* __restrict__ packed) {
    int wv = threadIdx.x >> 6, lane = threadIdx.x & 63;
    int row = blockIdx.x * PACK_ROWS + wv;        // one image row per wave
    const float* rbase = x + (size_t)row * WIDTH;
    u64* pbase = packed + (size_t)row * WPR;
    vfloat4 v[4];
    #pragma unroll
    for (int rnd = 0; rnd < 4; ++rnd)             // all 4 loads outstanding
        v[rnd] = *(const vfloat4*)(rbase + rnd * 256 + lane * 4);
    #pragma unroll
    for (int rnd = 0; rnd < 4; ++rnd) {           // 256 px per round
        unsigned nib = (v[rnd].x > 0.5f ? 1u : 0u) | (v[rnd].y > 0.5f ? 2u : 0u)
                     | (v[rnd].z > 0.5f ? 4u : 0u) | (v[rnd].w > 0.5f ? 8u : 0u);
        u64 n = (u64)nib << (4 * (lane & 15));
        n |= __shfl_xor(n, 1);                    // OR-reduce within 16-lane
        n |= __shfl_xor(n, 2);                    // groups: group g holds
        n |= __shfl_xor(n, 4);                    // px 256*rnd+64g..+63
        n |= __shfl_xor(n, 8);
        if ((lane & 15) == 0) pbase[rnd * 4 + (lane >> 4)] = n;
    }
}

// ---------------- wave-edge shuffles (zero beyond wave = halo/zero-pad) -------
__device__ __forceinline__ u64 sh_up(u64 x, int lane) {
    u64 t = __shfl(x, lane - 1);
    return lane == 0 ? 0ULL : t;
}
__device__ __forceinline__ u64 sh_dn(u64 x, int lane) {
    u64 t = __shfl(x, lane + 1);
    return lane == 63 ? 0ULL : t;
}

// One skeleton step, fully in registers. Bit (LSB) = leftmost pixel.
// hand: CM&1 -> sample x-1 = (c<<1)|(left>>63); vand: RM&1 -> row above.
// Dilate uses reflected kernel (offsets negated). Proven mapping from R6/R8.
template <int RM, int CM, bool DIL>
__device__ __forceinline__ void mstep(u64 (&B)[RPL][3], u64 (&O)[RPL][3], int lane) {
    u64 T[RPL][3], M[RPL][3];
    // horizontal erode
    #pragma unroll
    for (int s = 0; s < RPL; ++s) {
        #pragma unroll
        for (int j = 0; j < 3; ++j) {
            u64 c = B[s][j], res = ~0ULL;
            if (CM & 2) res &= c;
            if (CM & 1) res &= (c << 1) | ((j > 0 ? B[s][j - 1] : 0ULL) >> 63);
            if (CM & 4) res &= (c >> 1) | ((j < 2 ? B[s][j + 1] : 0ULL) << 63);
            T[s][j] = res;
        }
    }
    // vertical erode -> M, O
    #pragma unroll
    for (int j = 0; j < 3; ++j) {
        u64 up = sh_up(T[RPL - 1][j], lane);
        u64 dn = sh_dn(T[0][j], lane);
        #pragma unroll
        for (int s = 0; s < RPL; ++s) {
            u64 res = ~0ULL;
            if (RM & 2) res &= T[s][j];
            if (RM & 1) res &= (s > 0 ? T[s - 1][j] : up);
            if (RM & 4) res &= (s < RPL - 1 ? T[s + 1][j] : dn);
            M[s][j] = res;
            O[s][j] |= res;
        }
    }
    if (DIL) {
        // horizontal dilate (reflected)
        #pragma unroll
        for (int s = 0; s < RPL; ++s) {
            #pragma unroll
            for (int j = 0; j < 3; ++j) {
                u64 c = M[s][j], res = 0;
                if (CM & 2) res |= c;
                if (CM & 1) res |= (c >> 1) | ((j < 2 ? M[s][j + 1] : 0ULL) << 63);
                if (CM & 4) res |= (c << 1) | ((j > 0 ? M[s][j - 1] : 0ULL) >> 63);
                T[s][j] = res;
            }
        }
        // vertical dilate (reflected), subtract from B
        #pragma unroll
        for (int j = 0; j < 3; ++j) {
            u64 up = sh_up(T[RPL - 1][j], lane);
            u64 dn = sh_dn(T[0][j], lane);
            #pragma unroll
            for (int s = 0; s < RPL; ++s) {
                u64 res = 0;
                if (RM & 2) res |= T[s][j];
                if (RM & 1) res |= (s < RPL - 1 ? T[s + 1][j] : dn);
                if (RM & 4) res |= (s > 0 ? T[s - 1][j] : up);
                B[s][j] &= ~res;
            }
        }
    }
}

// ---------------- phase 2: register morphology + isolated-point + expand -----
__global__ __launch_bounds__(256) void regmorph_kernel(const u64* __restrict__ packed,
                                                       float* __restrict__ out) {
    __shared__ u64 stage[4][BVALID + 2];
    int lane = threadIdx.x & 63;
    int wv = threadIdx.x >> 6;
    int W = blockIdx.x * 4 + wv;                  // flat wave id, 0..2815
    int img  = W / (WPR * NBANDS);
    int rem  = W % (WPR * NBANDS);
    int wcol = rem / NBANDS;
    int band = rem % NBANDS;
    int bstart = band * BVALID - HALO;            // global row of v=0

    // load 2 rows x 3 words per lane, zero outside image (zero-pad semantics)
    const u64* pimg = packed + (size_t)img * HEIGHT * WPR;
    u64 B[RPL][3], O[RPL][3];
    #pragma unroll
    for (int s = 0; s < RPL; ++s) {
        int g = bstart + lane * RPL + s;
        bool rok = (g >= 0 && g < HEIGHT);
        #pragma unroll
        for (int j = 0; j < 3; ++j) {
            int wi = wcol - 1 + j;
            B[s][j] = (rok && wi >= 0 && wi < WPR) ? pimg[(size_t)g * WPR + wi] : 0ULL;
            O[s][j] = 0ULL;
        }
    }

    // 8 structuring elements as (rowmask, colmask) rectangles
    mstep<7, 7, true >(B, O, lane);   // all ones
    mstep<7, 6, true >(B, O, lane);   // cols {1,2}
    mstep<3, 7, true >(B, O, lane);   // rows {0,1}
    mstep<6, 6, true >(B, O, lane);   // rows {1,2} x cols {1,2}
    mstep<7, 2, true >(B, O, lane);   // col {1}
    mstep<2, 7, true >(B, O, lane);   // row {1}
    mstep<3, 2, true >(B, O, lane);   // col {1}, rows {0,1}
    mstep<2, 3, false>(B, O, lane);   // row {1}, cols {0,1}; B unused after

    // isolated-point: 3x3 popcount of O == 1, center word only (carry-save)
    u64 Wn[RPL], Cn[RPL], En[RPL], res[RPL];
    #pragma unroll
    for (int s = 0; s < RPL; ++s) {
        Cn[s] = O[s][1];
        Wn[s] = (O[s][1] << 1) | (O[s][0] >> 63);
        En[s] = (O[s][1] >> 1) | (O[s][2] << 63);
    }
    u64 upW = sh_up(Wn[RPL - 1], lane), upC = sh_up(Cn[RPL - 1], lane),
        upE = sh_up(En[RPL - 1], lane);
    u64 dnW = sh_dn(Wn[0], lane), dnC = sh_dn(Cn[0], lane), dnE = sh_dn(En[0], lane);
    #pragma unroll
    for (int s = 0; s < RPL; ++s) {
        u64 ones = 0, twos = 0;
        auto acc = [&](u64 v) { twos |= ones & v; ones ^= v; };
        acc(s > 0 ? Wn[s - 1] : upW);
        acc(s > 0 ? Cn[s - 1] : upC);
        acc(s > 0 ? En[s - 1] : upE);
        acc(Wn[s]); acc(Cn[s]); acc(En[s]);
        acc(s < RPL - 1 ? Wn[s + 1] : dnW);
        acc(s < RPL - 1 ? Cn[s + 1] : dnC);
        acc(s < RPL - 1 ? En[s + 1] : dnE);
        res[s] = ones & ~twos;
    }

    // stage valid rows (v in [HALO, HALO+BVALID)) into this wave's LDS slice
    #pragma unroll
    for (int s = 0; s < RPL; ++s) {
        int v = lane * RPL + s;
        if (v >= HALO && v < HALO + BVALID) stage[wv][v - HALO] = res[s];
    }
    __syncthreads();   // uniform across all 4 waves

    // expand to f32, coalesced: per instr 4 rows x 16 lanes x 16 B (full lines)
    int gbase = band * BVALID;
    float* obase = out + (size_t)img * HEIGHT * WIDTH + wcol * 64 + (lane & 15) * 4;
    for (int it = 0; it < (BVALID + 3) / 4; ++it) {
        int t = it * 4 + (lane >> 4);
        int g = gbase + t;
        if (t < BVALID && g < HEIGHT) {
            u64 word = stage[wv][t];
            unsigned nib = (unsigned)(word >> ((lane & 15) * 4)) & 15u;
            vfloat4 v4;
            v4.x = (nib & 1) ? 1.f : 0.f;
            v4.y = (nib & 2) ? 1.f : 0.f;
            v4.z = (nib & 4) ? 1.f : 0.f;
            v4.w = (nib & 8) ? 1.f : 0.f;
            __builtin_nontemporal_store(v4, (vfloat4*)(obase + (size_t)g * WIDTH));
        }
    }
}

extern "C" void kernel_launch(void* const* d_in, const int* in_sizes, int n_in,
                              void* d_out, int out_size, void* d_ws, size_t ws_size,
                              hipStream_t stream) {
    const float* x = (const float*)d_in[0];
    float* out = (float*)d_out;
    u64* packed = (u64*)d_ws;   // NIMG*HEIGHT*WPR*8 = 2 MiB used

    hipLaunchKernelGGL(pack_kernel, dim3(NIMG * HEIGHT / PACK_ROWS), dim3(256), 0,
                       stream, x, packed);
    hipLaunchKernelGGL(regmorph_kernel,
                       dim3(NIMG * WPR * NBANDS / 4), dim3(256), 0, stream,
                       packed, out);
}